// Round 1
// baseline (537.358 us; speedup 1.0000x reference)
//
#include <hip/hip_runtime.h>
#include <math.h>

#define NCLASS 10
#define NFEAT  64

// workspace layout (float offsets)
#define OFF_M    0                       // [10][64][64] raw second moments (atomic accum)
#define OFF_S    40960                   // [10][64] per-class sums (atomic accum)
#define OFF_CNT  41600                   // [10] counts as float (atomic accum)
#define OFF_SC   41616                   // [10][64][64] covariances
#define OFF_MU   (OFF_SC + 40960)        // [10][64]
#define OFF_LDC  (OFF_MU + 640)          // [10] logdet per class
#define OFF_PM   (OFF_LDC + 16)          // [45] pair maha
#define OFF_PL   (OFF_PM + 48)           // [45] pair logdet
#define ZERO_CNT OFF_SC                  // zero [0, OFF_SC)

// ---------------------------------------------------------------- k0: zero accumulators
__global__ void k0_zero(float* __restrict__ ws) {
  int i = blockIdx.x * blockDim.x + threadIdx.x;
  if (i < ZERO_CNT) ws[i] = 0.0f;
}

// ---------------------------------------------------------------- k1: per-class moments
// 640 threads = 10 waves; wave w owns class w. Lane j accumulates M[c][r][j] for r=0..63.
__global__ __launch_bounds__(640) void k1_moments(const float* __restrict__ X,
                                                  const int* __restrict__ T,
                                                  float* __restrict__ ws,
                                                  int N, int chunk) {
  const int c    = threadIdx.x >> 6;   // class = wave id
  const int lane = threadIdx.x & 63;
  int rowStart = blockIdx.x * chunk;
  int rowEnd   = rowStart + chunk; if (rowEnd > N) rowEnd = N;

  float acc[64];
#pragma unroll
  for (int r = 0; r < 64; ++r) acc[r] = 0.0f;
  float accS = 0.0f;
  int   cnt  = 0;

  int base = rowStart;
  for (; base + 8 <= rowEnd; base += 8) {
    // batch-load 8 targets (amortize latency); values are wave-uniform
    int4 ta = *(const int4*)(T + base);
    int4 tb = *(const int4*)(T + base + 4);
    int ts[8] = { ta.x, ta.y, ta.z, ta.w, tb.x, tb.y, tb.z, tb.w };
#pragma unroll
    for (int u = 0; u < 8; ++u) {
      if (__builtin_amdgcn_readfirstlane(ts[u]) != c) continue;   // uniform branch
      const float*  row  = X + (size_t)(base + u) * NFEAT;
      const float4* row4 = (const float4*)row;
      float vx = row[lane];                 // coalesced 256B: lane j gets x[j]
      cnt++; accS += vx;
#pragma unroll
      for (int k = 0; k < 16; ++k) {        // uniform-address broadcast loads
        float4 b = row4[k];
        acc[4*k+0] += b.x * vx;
        acc[4*k+1] += b.y * vx;
        acc[4*k+2] += b.z * vx;
        acc[4*k+3] += b.w * vx;
      }
    }
  }
  for (; base < rowEnd; ++base) {          // tail (not hit for N=524288)
    int t = __builtin_amdgcn_readfirstlane(T[base]);
    if (t != c) continue;
    const float*  row  = X + (size_t)base * NFEAT;
    const float4* row4 = (const float4*)row;
    float vx = row[lane];
    cnt++; accS += vx;
#pragma unroll
    for (int k = 0; k < 16; ++k) {
      float4 b = row4[k];
      acc[4*k+0] += b.x * vx;
      acc[4*k+1] += b.y * vx;
      acc[4*k+2] += b.z * vx;
      acc[4*k+3] += b.w * vx;
    }
  }

  float* M = ws + OFF_M + c * 4096;
#pragma unroll
  for (int r = 0; r < 64; ++r)
    atomicAdd(&M[r * 64 + lane], acc[r]);    // lanes contiguous -> coalesced atomics
  atomicAdd(&ws[OFF_S + c * 64 + lane], accS);
  if (lane == 0) atomicAdd(&ws[OFF_CNT + c], (float)cnt);
}

// ---------------------------------------------------------------- k2a: mu + covariance
__global__ void k2a_cov(float* __restrict__ ws) {
  const int c = blockIdx.x, tid = threadIdx.x;
  __shared__ float mu[64];
  float cnt = ws[OFF_CNT + c];
  if (tid < 64) {
    float m = ws[OFF_S + c * 64 + tid] / cnt;
    mu[tid] = m;
    ws[OFF_MU + c * 64 + tid] = m;
  }
  __syncthreads();
  float inv = 1.0f / (cnt - 1.0f);
  for (int idx = tid; idx < 4096; idx += blockDim.x) {
    int r = idx >> 6, l = idx & 63;
    ws[OFF_SC + c * 4096 + idx] =
        (ws[OFF_M + c * 4096 + idx] - cnt * mu[r] * mu[l]) * inv;
  }
}

// ---------------------------------------------------------------- k2b: Cholesky blocks
// blocks 0..9: logdet(Sc[c]).  blocks 10..54: pair (i<j): Spair=0.5(Sc_i+Sc_j),
// logdet_pair and maha = |L^{-1} dmu|^2 / 8.  Single wave (64 threads) per block.
__global__ void k2b_chol(float* __restrict__ ws) {
  __shared__ float S[64][65];
  __shared__ float ybuf[64];
  const int lane = threadIdx.x;
  const int bid  = blockIdx.x;

  int ci, cj, p = -1;
  bool isPair = (bid >= NCLASS);
  if (!isPair) { ci = cj = bid; }
  else {
    p = bid - NCLASS;
    int rem = p, i = 0;
    while (rem >= 9 - i) { rem -= 9 - i; ++i; }
    ci = i; cj = i + 1 + rem;
  }

  const float* A = ws + OFF_SC + ci * 4096;
  const float* B = ws + OFF_SC + cj * 4096;
  for (int r = 0; r < 64; ++r) {
    float v = A[r * 64 + lane];
    if (isPair) v = 0.5f * (v + B[r * 64 + lane]);
    S[r][lane] = v;
  }
  float d = 0.0f;
  if (isPair) d = ws[OFF_MU + ci * 64 + lane] - ws[OFF_MU + cj * 64 + lane];
  __syncthreads();

  // in-place lower Cholesky (right-looking)
  for (int k = 0; k < 64; ++k) {
    float Lkk = sqrtf(S[k][k]);
    float Lik = 0.0f;
    if (lane > k) Lik = S[lane][k] / Lkk;
    __syncthreads();
    if (lane == k) S[k][k] = Lkk;
    if (lane > k)  S[lane][k] = Lik;
    __syncthreads();
    for (int j = k + 1; j <= lane; ++j)     // update own row, lower part
      S[lane][j] -= Lik * S[j][k];
    __syncthreads();
  }

  // logdet = 2 * sum log(diag)
  float lv = logf(S[lane][lane]);
#pragma unroll
  for (int off = 32; off > 0; off >>= 1) lv += __shfl_down(lv, off, 64);
  // lane 0 now holds sum

  if (isPair) {
    // forward solve L y = d
    float pi = d;
    for (int k = 0; k < 64; ++k) {
      if (lane == k) ybuf[k] = pi / S[k][k];
      __syncthreads();
      float yk = ybuf[k];
      if (lane > k) pi -= S[lane][k] * yk;
      __syncthreads();
    }
    float yv = ybuf[lane];
    float s2 = yv * yv;
#pragma unroll
    for (int off = 32; off > 0; off >>= 1) s2 += __shfl_down(s2, off, 64);
    if (lane == 0) {
      ws[OFF_PM + p] = s2 * 0.125f;
      ws[OFF_PL + p] = 2.0f * lv;
    }
  } else {
    if (lane == 0) ws[OFF_LDC + bid] = 2.0f * lv;
  }
}

// ---------------------------------------------------------------- k2c: final scalar
__global__ void k2c_final(const float* __restrict__ Ksamp,
                          const float* __restrict__ ws,
                          float* __restrict__ out) {
  __shared__ double ldc[10], pm[45], pl[45];
  __shared__ double Km[100], Sp[100], L[100], Inv[100], Aa[100];
  __shared__ double yv[10], xv[10];
  const int tid = threadIdx.x;

  if (tid < 10) ldc[tid] = (double)ws[OFF_LDC + tid];
  if (tid < 45) { pm[tid] = (double)ws[OFF_PM + tid]; pl[tid] = (double)ws[OFF_PL + tid]; }
  if (tid < 100) Sp[tid] = (double)Ksamp[tid];
  __syncthreads();

  double s00 = Sp[0];
  if (tid < 100) {
    int i = tid / 10, j = tid % 10;
    double Kv;
    if (i == j) Kv = s00 * (0.5 * 1.0 + 0.5);
    else {
      int a = i < j ? i : j, b = i < j ? j : i;
      int pp = (a * (19 - a)) / 2 + (b - a - 1);
      double D = pm[pp] + 0.5 * (pl[pp] - 0.5 * (ldc[i] + ldc[j]));
      Kv = s00 * (0.5 * exp(-D * D * 100.0));
    }
    Km[tid] = Kv;
  }
  __syncthreads();

  if (tid == 0) {
    const int k = 10;
    // Cholesky of Sp
    for (int kk = 0; kk < k; ++kk) {
      double s = Sp[kk * k + kk];
      for (int m = 0; m < kk; ++m) s -= L[kk * k + m] * L[kk * k + m];
      double Lkk = sqrt(s);
      L[kk * k + kk] = Lkk;
      for (int r = kk + 1; r < k; ++r) {
        double v = Sp[r * k + kk];
        for (int m = 0; m < kk; ++m) v -= L[r * k + m] * L[kk * k + m];
        L[r * k + kk] = v / Lkk;
      }
    }
    double ldSp = 0.0;
    for (int kk = 0; kk < k; ++kk) ldSp += 2.0 * log(L[kk * k + kk]);

    // Inv = Sp^{-1} by column solves
    for (int e = 0; e < k; ++e) {
      for (int r = 0; r < k; ++r) {
        double v = (r == e) ? 1.0 : 0.0;
        for (int m = 0; m < r; ++m) v -= L[r * k + m] * yv[m];
        yv[r] = v / L[r * k + r];
      }
      for (int r = k - 1; r >= 0; --r) {
        double v = yv[r];
        for (int m = r + 1; m < k; ++m) v -= L[m * k + r] * xv[m];
        xv[r] = v / L[r * k + r];
      }
      for (int r = 0; r < k; ++r) Inv[r * k + e] = xv[r];
    }
    double trace = 0.0;
    for (int t = 0; t < 100; ++t) trace += Inv[t] * Km[t];

    // logdet(K_) via LU with partial pivoting
    for (int t = 0; t < 100; ++t) Aa[t] = Km[t];
    double ldK = 0.0;
    for (int kk = 0; kk < k; ++kk) {
      int piv = kk; double mx = fabs(Aa[kk * k + kk]);
      for (int r = kk + 1; r < k; ++r) {
        double v = fabs(Aa[r * k + kk]);
        if (v > mx) { mx = v; piv = r; }
      }
      if (piv != kk)
        for (int c2 = 0; c2 < k; ++c2) {
          double tmp = Aa[kk * k + c2]; Aa[kk * k + c2] = Aa[piv * k + c2]; Aa[piv * k + c2] = tmp;
        }
      ldK += log(fabs(Aa[kk * k + kk]));
      for (int r = kk + 1; r < k; ++r) {
        double f = Aa[r * k + kk] / Aa[kk * k + kk];
        for (int c2 = kk + 1; c2 < k; ++c2) Aa[r * k + c2] -= f * Aa[kk * k + c2];
      }
    }

    double kl = 0.5 * (trace - (double)k + ldSp - ldK);
    out[0] = (float)kl;
  }
}

// ---------------------------------------------------------------- launch
extern "C" void kernel_launch(void* const* d_in, const int* in_sizes, int n_in,
                              void* d_out, int out_size, void* d_ws, size_t ws_size,
                              hipStream_t stream) {
  const float* X  = (const float*)d_in[0];
  const int*   T  = (const int*)d_in[1];
  const float* Ks = (const float*)d_in[2];
  float* out = (float*)d_out;
  float* ws  = (float*)d_ws;
  int N = in_sizes[1];

  // k0: zero atomic accumulators
  {
    int blocks = (ZERO_CNT + 255) / 256;
    k0_zero<<<blocks, 256, 0, stream>>>(ws);
  }
  // k1: moments
  {
    int grid = 512;
    int chunk = (N + grid - 1) / grid;
    chunk = (chunk + 7) & ~7;
    k1_moments<<<grid, 640, 0, stream>>>(X, T, ws, N, chunk);
  }
  // k2a: covariance
  k2a_cov<<<NCLASS, 256, 0, stream>>>(ws);
  // k2b: Cholesky blocks (10 class + 45 pairs)
  k2b_chol<<<55, 64, 0, stream>>>(ws);
  // k2c: final scalar
  k2c_final<<<1, 128, 0, stream>>>(Ks, ws, out);
}